// Round 17
// baseline (213.540 us; speedup 1.0000x reference)
//
#include <hip/hip_runtime.h>
#include <math.h>

#define N_NODES 50000
#define DIM 64
#define NE 800000
#define NSCAN_BLOCKS ((N_NODES + 255) / 256)   // 196
#define NGROUPS 8                               // row-groups ~ XCDs
#define ROWS_PER_GROUP ((N_NODES + NGROUPS - 1) / NGROUPS)   // 6250
#define NFILL_GRID (392 * NGROUPS)              // 3136 blocks

static __device__ __forceinline__ unsigned short f2bf(float f) {
    unsigned int u = __float_as_uint(f);
    u += 0x7fffu + ((u >> 16) & 1u);
    return (unsigned short)(u >> 16);
}
static __device__ __forceinline__ float bf2f(unsigned short u) {
    return __uint_as_float(((unsigned int)u) << 16);
}

typedef _Float16 half2v __attribute__((ext_vector_type(2)));
typedef float v2f __attribute__((ext_vector_type(2)));

static __device__ __forceinline__ half2v u2h(unsigned int u) {
    union { unsigned int u; half2v h; } x; x.u = u; return x.h;
}
static __device__ __forceinline__ unsigned short f2h(float f) {
    union { _Float16 h; unsigned short s; } x; x.h = (_Float16)f; return x.s;
}

#if defined(__has_builtin)
#  if __has_builtin(__builtin_amdgcn_fdot2)
#    define HAVE_FDOT2 1
#  endif
#endif

// acc += dot(f16x2, f16x2) — v_dot2_f32_f16 when available
static __device__ __forceinline__ float dot2acc(unsigned int qa,
                                                unsigned int ka, float c) {
#ifdef HAVE_FDOT2
    return __builtin_amdgcn_fdot2(u2h(qa), u2h(ka), c, false);
#else
    half2v q = u2h(qa), k = u2h(ka);
    return c + (float)q.x * (float)k.x + (float)q.y * (float)k.y;
#endif
}

// decode 2 fp8(e4m3) from dword half (HI must be literal)
template <bool HI>
static __device__ __forceinline__ v2f fp8x2(unsigned int u) {
    return __builtin_amdgcn_cvt_pk_f32_fp8((int)u, HI);
}
// pack 4 floats -> 4 fp8 bytes in one dword
static __device__ __forceinline__ unsigned int pack4_fp8(float a, float b,
                                                         float c, float d) {
    int p = __builtin_amdgcn_cvt_pk_fp8_f32(a, b, 0, false);
    p = __builtin_amdgcn_cvt_pk_fp8_f32(c, d, p, true);
    return (unsigned int)p;
}

// ---------------------------------------------------------------------------
// ws layout:
//   Qh   : N*64 ushorts   (f16, pre-scaled by log2(e); wave-uniform read)
//   KVC  : N rows x 256B  (K f16 128B | V,C fp8 dword-interleaved 128B)
//   bucket_col : NE ints
//   counts  : N ints (doubles as fill cursor)
//   offsets : N+1 ints
//   bsums   : 256 ints
//   wsum    : N floats
//   S       : 1 float
// Lessons: single-address f32 atomicAdd ~13ns serialized (50k waves = 580us)
// [R10]; LDS-heavy kernel fused with scatter = occupancy kill [R13];
// sub-dword scatter stores = 16x line write amplification [R13/R14];
// row-group partition makes scatter L2-local (fill 61->~15us) [R15];
// edge kernel is latency-limited at VALUBusy~63% [R16].
// ---------------------------------------------------------------------------

// QKV projections: 32 nodes/block, bf16 weights in LDS, 8 nodes/thread.
__global__ __launch_bounds__(256, 5) void k_qkv(
    const float* __restrict__ x, const float* __restrict__ coord,
    const float* __restrict__ Wq, const float* __restrict__ bq,
    const float* __restrict__ Wk, const float* __restrict__ bk,
    const float* __restrict__ Wv, const float* __restrict__ bv,
    unsigned short* __restrict__ Qh, unsigned short* __restrict__ KVC)
{
    __shared__ ushort4 WT2[3][1024];  // 24 KB bf16 weights
    __shared__ float4  xs4[32][16];   // 8 KB (reused as V stage after compute)

    const int tid  = threadIdx.x;
    const int base = blockIdx.x * 32;

    for (int t = tid; t < 1024; t += 256) {
        int d = t & 63, j2 = t >> 6;
        float4 a = ((const float4*)Wq)[d * 16 + j2];
        float4 b = ((const float4*)Wk)[d * 16 + j2];
        float4 c = ((const float4*)Wv)[d * 16 + j2];
        WT2[0][t] = make_ushort4(f2bf(a.x), f2bf(a.y), f2bf(a.z), f2bf(a.w));
        WT2[1][t] = make_ushort4(f2bf(b.x), f2bf(b.y), f2bf(b.z), f2bf(b.w));
        WT2[2][t] = make_ushort4(f2bf(c.x), f2bf(c.y), f2bf(c.z), f2bf(c.w));
    }
    for (int t = tid; t < 512; t += 256) {
        int r = t >> 4, j2 = t & 15;
        if (base + r < N_NODES)
            xs4[r][j2] = ((const float4*)x)[(size_t)(base + r) * 16 + j2];
    }
    __syncthreads();

    const int wv = tid >> 6;
    const int d  = tid & 63;
    const float bqv = bq[d], bkv = bk[d], bvv = bv[d];

    float aq[8], ak[8], av[8];
    #pragma unroll
    for (int r = 0; r < 8; ++r) { aq[r] = bqv; ak[r] = bkv; av[r] = bvv; }

    #pragma unroll 4
    for (int j2 = 0; j2 < 16; ++j2) {
        ushort4 uq = WT2[0][j2 * 64 + d];
        ushort4 uk = WT2[1][j2 * 64 + d];
        ushort4 uv = WT2[2][j2 * 64 + d];
        float wqx = bf2f(uq.x), wqy = bf2f(uq.y), wqz = bf2f(uq.z), wqw = bf2f(uq.w);
        float wkx = bf2f(uk.x), wky = bf2f(uk.y), wkz = bf2f(uk.z), wkw = bf2f(uk.w);
        float wvx = bf2f(uv.x), wvy = bf2f(uv.y), wvz = bf2f(uv.z), wvw = bf2f(uv.w);
        #pragma unroll
        for (int r = 0; r < 8; ++r) {
            float4 xv = xs4[wv * 8 + r][j2];   // wave-uniform broadcast
            aq[r] += xv.x * wqx + xv.y * wqy + xv.z * wqz + xv.w * wqw;
            ak[r] += xv.x * wkx + xv.y * wky + xv.z * wkz + xv.w * wkw;
            av[r] += xv.x * wvx + xv.y * wvy + xv.z * wvz + xv.w * wvw;
        }
    }
    // Q (f16, pre-scaled by log2e) and K (f16) stores: coalesced 128B/wave
    #pragma unroll
    for (int r = 0; r < 8; ++r) {
        int n = base + wv * 8 + r;
        if (n < N_NODES) {
            Qh[(size_t)n * 64 + d]  = f2h(aq[r] * 1.44269504f);
            KVC[(size_t)n * 128 + d] = f2h(ak[r]);
        }
    }
    // V: stage f32 in LDS, then pack {V,C} fp8 dwords -> one uint2 store
    __syncthreads();   // all xs4 reads done
    float* vf = (float*)xs4;
    #pragma unroll
    for (int r = 0; r < 8; ++r)
        vf[(wv * 8 + r) * 64 + d] = av[r];
    __syncthreads();
    uint2* VC2 = (uint2*)KVC;           // row = 32 uint2 (256B)
    for (int t = tid; t < 512; t += 256) {
        int ln = t >> 4, j = t & 15;
        int n = base + ln;
        if (n < N_NODES) {
            float4 vv = ((const float4*)vf)[ln * 16 + j];
            float4 cv = ((const float4*)coord)[(size_t)n * 16 + j];
            uint2 o;
            o.x = pack4_fp8(vv.x, vv.y, vv.z, vv.w);
            o.y = pack4_fp8(cv.x, cv.y, cv.z, cv.w);
            VC2[(size_t)n * 32 + 16 + j] = o;
        }
    }
}

// Row-group-partitioned histogram (group ~ XCD; atomics L2-local)
__global__ __launch_bounds__(256) void k_hist(
    const int* __restrict__ eidx, int* __restrict__ counts)
{
    const int grp = blockIdx.x & (NGROUPS - 1);
    const int blk = blockIdx.x >> 3;
    const int nblk = gridDim.x >> 3;
    const int rlo = grp * ROWS_PER_GROUP;
    const int rhi = rlo + ROWS_PER_GROUP;
    for (int e = blk * 256 + threadIdx.x; e < NE; e += nblk * 256) {
        int r = eidx[e];
        if (r >= rlo && r < rhi) atomicAdd(counts + r, 1);
    }
}

__global__ __launch_bounds__(256) void k_scan1(
    const int* __restrict__ counts, int* __restrict__ offsets,
    int* __restrict__ bsums)
{
    __shared__ int tmp[256];
    int i = blockIdx.x * 256 + threadIdx.x;
    int v = (i < N_NODES) ? counts[i] : 0;
    tmp[threadIdx.x] = v;
    __syncthreads();
    #pragma unroll
    for (int off = 1; off < 256; off <<= 1) {
        int t = (threadIdx.x >= off) ? tmp[threadIdx.x - off] : 0;
        __syncthreads();
        tmp[threadIdx.x] += t;
        __syncthreads();
    }
    if (i < N_NODES) offsets[i] = tmp[threadIdx.x] - v;   // exclusive
    if (threadIdx.x == 255) bsums[blockIdx.x] = tmp[255];
}

// merged scan2+scan3
__global__ __launch_bounds__(256) void k_scan23(
    int* __restrict__ offsets, int* __restrict__ counts,
    const int* __restrict__ bsums)
{
    __shared__ int red[4];
    const int tid = threadIdx.x;
    const int b   = blockIdx.x;
    int v = (tid < b && tid < NSCAN_BLOCKS) ? bsums[tid] : 0;
    #pragma unroll
    for (int off = 32; off; off >>= 1) v += __shfl_xor(v, off);
    if ((tid & 63) == 0) red[tid >> 6] = v;
    __syncthreads();
    const int pre = red[0] + red[1] + red[2] + red[3];

    int i = b * 256 + tid;
    if (i < N_NODES) {
        int o = offsets[i] + pre;
        offsets[i] = o;
        counts[i]  = o;     // cursor for fill
    }
    if (i == 0) offsets[N_NODES] = NE;
}

// Row-group-partitioned fill (writes L2-local -> no 16x amplification)
__global__ __launch_bounds__(256) void k_fill(
    const int* __restrict__ eidx, int* __restrict__ cursor,
    int* __restrict__ bucket_col)
{
    const int grp = blockIdx.x & (NGROUPS - 1);
    const int blk = blockIdx.x >> 3;
    const int nblk = gridDim.x >> 3;
    const int rlo = grp * ROWS_PER_GROUP;
    const int rhi = rlo + ROWS_PER_GROUP;
    const int* __restrict__ cols = eidx + NE;
    for (int e = blk * 256 + threadIdx.x; e < NE; e += nblk * 256) {
        int r = eidx[e];
        if (r >= rlo && r < rhi) {
            int pos = atomicAdd(cursor + r, 1);
            bucket_col[pos] = cols[e];
        }
    }
}

// Fused edge pass: wave per node, 16-lane quarter per edge, lane = 4 dims,
// 4x unrolled (16 edges / 8 KVC loads in flight — latency-limited at 2x
// [R16: VALUBusy 63%, HBM 22%]). K f16 (fdot2), V/C fp8 (one uint2 load).
__global__ __launch_bounds__(256) void k_edge_fused(
    const int* __restrict__ bucket_col, const int* __restrict__ offsets,
    const unsigned short* __restrict__ Qh, const unsigned short* __restrict__ KVC,
    const float* __restrict__ coord,
    const float* __restrict__ Wc, const float* __restrict__ bc,
    float* __restrict__ out_x, float* __restrict__ out_c,
    float* __restrict__ wsum)
{
    const int lane = threadIdx.x & 63;
    const int n = (blockIdx.x * 256 + threadIdx.x) >> 6;
    if (n >= N_NODES) return;
    const int qt = lane >> 4;          // quarter: which edge of the group of 4
    const int sl = lane & 15;          // dim-quad slot (dims 4sl..4sl+3)

    const uint2 q2   = ((const uint2*)Qh)[(size_t)n * 16 + sl];   // 2x f16x2
    const float4 cr4 = ((const float4*)coord)[(size_t)n * 16 + sl];
    const float4 wc4 = ((const float4*)Wc)[sl];
    const float4 bc4 = ((const float4*)bc)[sl];
    const uint2* K2  = (const uint2*)KVC;    // K: idx c*32 + sl
    const uint2* VC2 = (const uint2*)KVC;    // VC: idx c*32 + 16 + sl

    const int s = offsets[n], t = offsets[n + 1];
    float4 accx = {0.f, 0.f, 0.f, 0.f};
    float4 accc = {0.f, 0.f, 0.f, 0.f};
    float psum = 0.0f;

    for (int base = s; base < t; base += 16) {
        int pos0 = base + qt;
        int pos1 = base + 4 + qt;
        int pos2 = base + 8 + qt;
        int pos3 = base + 12 + qt;
        bool v0 = pos0 < t, v1 = pos1 < t, v2 = pos2 < t, v3 = pos3 < t;
        int c0 = bucket_col[v0 ? pos0 : (t - 1)];
        int c1 = bucket_col[v1 ? pos1 : (t - 1)];
        int c2 = bucket_col[v2 ? pos2 : (t - 1)];
        int c3 = bucket_col[v3 ? pos3 : (t - 1)];
        // issue all 8 row loads up front (MLP)
        uint2 k0  = K2[(size_t)c0 * 32 + sl];
        uint2 k1  = K2[(size_t)c1 * 32 + sl];
        uint2 k2  = K2[(size_t)c2 * 32 + sl];
        uint2 k3  = K2[(size_t)c3 * 32 + sl];
        uint2 vc0 = VC2[(size_t)c0 * 32 + 16 + sl];
        uint2 vc1 = VC2[(size_t)c1 * 32 + 16 + sl];
        uint2 vc2 = VC2[(size_t)c2 * 32 + 16 + sl];
        uint2 vc3 = VC2[(size_t)c3 * 32 + 16 + sl];

        // logits via f16 dot2 (Q pre-scaled by log2e -> exp2 later)
        float d0 = dot2acc(q2.y, k0.y, dot2acc(q2.x, k0.x, 0.0f));
        float d1 = dot2acc(q2.y, k1.y, dot2acc(q2.x, k1.x, 0.0f));
        float d2 = dot2acc(q2.y, k2.y, dot2acc(q2.x, k2.x, 0.0f));
        float d3 = dot2acc(q2.y, k3.y, dot2acc(q2.x, k3.x, 0.0f));

        v2f c0a = fp8x2<false>(vc0.y), c0b = fp8x2<true>(vc0.y);
        v2f c1a = fp8x2<false>(vc1.y), c1b = fp8x2<true>(vc1.y);
        v2f c2a = fp8x2<false>(vc2.y), c2b = fp8x2<true>(vc2.y);
        v2f c3a = fp8x2<false>(vc3.y), c3b = fp8x2<true>(vc3.y);

        float dx0x = cr4.x - c0a.x, dx0y = cr4.y - c0a.y;
        float dx0z = cr4.z - c0b.x, dx0w = cr4.w - c0b.y;
        float e0 = dx0x * dx0x + dx0y * dx0y + dx0z * dx0z + dx0w * dx0w;
        float dx1x = cr4.x - c1a.x, dx1y = cr4.y - c1a.y;
        float dx1z = cr4.z - c1b.x, dx1w = cr4.w - c1b.y;
        float e1 = dx1x * dx1x + dx1y * dx1y + dx1z * dx1z + dx1w * dx1w;
        float dx2x = cr4.x - c2a.x, dx2y = cr4.y - c2a.y;
        float dx2z = cr4.z - c2b.x, dx2w = cr4.w - c2b.y;
        float e2 = dx2x * dx2x + dx2y * dx2y + dx2z * dx2z + dx2w * dx2w;
        float dx3x = cr4.x - c3a.x, dx3y = cr4.y - c3a.y;
        float dx3z = cr4.z - c3b.x, dx3w = cr4.w - c3b.y;
        float e3 = dx3x * dx3x + dx3y * dx3y + dx3z * dx3z + dx3w * dx3w;

        #pragma unroll
        for (int off = 1; off <= 8; off <<= 1) {   // reduce within quarter
            d0 += __shfl_xor(d0, off);
            e0 += __shfl_xor(e0, off);
            d1 += __shfl_xor(d1, off);
            e1 += __shfl_xor(e1, off);
            d2 += __shfl_xor(d2, off);
            e2 += __shfl_xor(e2, off);
            d3 += __shfl_xor(d3, off);
            e3 += __shfl_xor(e3, off);
        }
        float p0e = v0 ? exp2f(d0) : 0.0f;
        float p1e = v1 ? exp2f(d1) : 0.0f;
        float p2e = v2 ? exp2f(d2) : 0.0f;
        float p3e = v3 ? exp2f(d3) : 0.0f;
        float dist0 = sqrtf(e0), dist1 = sqrtf(e1);
        float dist2 = sqrtf(e2), dist3 = sqrtf(e3);
        psum += (p0e + p1e) + (p2e + p3e);

        v2f v0a = fp8x2<false>(vc0.x), v0b = fp8x2<true>(vc0.x);
        v2f v1a = fp8x2<false>(vc1.x), v1b = fp8x2<true>(vc1.x);
        v2f v2a = fp8x2<false>(vc2.x), v2b = fp8x2<true>(vc2.x);
        v2f v3a = fp8x2<false>(vc3.x), v3b = fp8x2<true>(vc3.x);
        accx.x += p0e * v0a.x + p1e * v1a.x + p2e * v2a.x + p3e * v3a.x;
        accx.y += p0e * v0a.y + p1e * v1a.y + p2e * v2a.y + p3e * v3a.y;
        accx.z += p0e * v0b.x + p1e * v1b.x + p2e * v2b.x + p3e * v3b.x;
        accx.w += p0e * v0b.y + p1e * v1b.y + p2e * v2b.y + p3e * v3b.y;
        float g0 = dist0, g1 = dist1, g2 = dist2, g3 = dist3;
        accc.x += p0e * (g0 * wc4.x + bc4.x) * dx0x
                + p1e * (g1 * wc4.x + bc4.x) * dx1x
                + p2e * (g2 * wc4.x + bc4.x) * dx2x
                + p3e * (g3 * wc4.x + bc4.x) * dx3x;
        accc.y += p0e * (g0 * wc4.y + bc4.y) * dx0y
                + p1e * (g1 * wc4.y + bc4.y) * dx1y
                + p2e * (g2 * wc4.y + bc4.y) * dx2y
                + p3e * (g3 * wc4.y + bc4.y) * dx3y;
        accc.z += p0e * (g0 * wc4.z + bc4.z) * dx0z
                + p1e * (g1 * wc4.z + bc4.z) * dx1z
                + p2e * (g2 * wc4.z + bc4.z) * dx2z
                + p3e * (g3 * wc4.z + bc4.z) * dx3z;
        accc.w += p0e * (g0 * wc4.w + bc4.w) * dx0w
                + p1e * (g1 * wc4.w + bc4.w) * dx1w
                + p2e * (g2 * wc4.w + bc4.w) * dx2w
                + p3e * (g3 * wc4.w + bc4.w) * dx3w;
    }

    // cross-quarter combine (once per node)
    #pragma unroll
    for (int off = 16; off <= 32; off <<= 1) {
        accx.x += __shfl_xor(accx.x, off);
        accx.y += __shfl_xor(accx.y, off);
        accx.z += __shfl_xor(accx.z, off);
        accx.w += __shfl_xor(accx.w, off);
        accc.x += __shfl_xor(accc.x, off);
        accc.y += __shfl_xor(accc.y, off);
        accc.z += __shfl_xor(accc.z, off);
        accc.w += __shfl_xor(accc.w, off);
        psum   += __shfl_xor(psum, off);
    }
    if (lane < 16) {
        ((float4*)out_x)[(size_t)n * 16 + sl] = accx;   // unnormalized
        ((float4*)out_c)[(size_t)n * 16 + sl] = accc;
    }
    if (lane == 0) wsum[n] = psum;
}

// deterministic fixed-tree reduction of wsum -> S (single block)
__global__ __launch_bounds__(1024) void k_redsum(
    const float* __restrict__ wsum, float* __restrict__ S)
{
    __shared__ float red[16];
    float a = 0.0f;
    for (int i = threadIdx.x; i < N_NODES; i += 1024) a += wsum[i];
    #pragma unroll
    for (int off = 32; off; off >>= 1) a += __shfl_xor(a, off);
    if ((threadIdx.x & 63) == 0) red[threadIdx.x >> 6] = a;
    __syncthreads();
    if (threadIdx.x == 0) {
        float s = 0.0f;
        #pragma unroll
        for (int w = 0; w < 16; ++w) s += red[w];
        *S = s;
    }
}

// out = residual + out * (1/S), one float4 per thread
__global__ __launch_bounds__(256) void k_finalize(
    const float* __restrict__ x, const float* __restrict__ coord,
    const float* __restrict__ S, float* __restrict__ out)
{
    const float inv = 1.0f / *S;
    const int nd4 = (N_NODES * DIM) / 4;      // 800000
    const float4* x4 = (const float4*)x;
    const float4* c4 = (const float4*)coord;
    float4* o4 = (float4*)out;
    int i = blockIdx.x * 256 + threadIdx.x;
    if (i < 2 * nd4) {
        float4 r = (i < nd4) ? x4[i] : c4[i - nd4];
        float4 a = o4[i];
        a.x = r.x + a.x * inv;
        a.y = r.y + a.y * inv;
        a.z = r.z + a.z * inv;
        a.w = r.w + a.w * inv;
        o4[i] = a;
    }
}

extern "C" void kernel_launch(void* const* d_in, const int* in_sizes, int n_in,
                              void* d_out, int out_size, void* d_ws, size_t ws_size,
                              hipStream_t stream)
{
    const float* x     = (const float*)d_in[0];
    const float* coord = (const float*)d_in[1];
    const float* Wq    = (const float*)d_in[2];
    const float* bq    = (const float*)d_in[3];
    const float* Wk    = (const float*)d_in[4];
    const float* bk    = (const float*)d_in[5];
    const float* Wv    = (const float*)d_in[6];
    const float* bv    = (const float*)d_in[7];
    const float* Wc    = (const float*)d_in[8];
    const float* bc    = (const float*)d_in[9];
    const int*   eidx  = (const int*)d_in[10];

    float* out = (float*)d_out;
    float* ws  = (float*)d_ws;

    unsigned short* Qh  = (unsigned short*)ws;
    unsigned short* KVC = Qh + (size_t)N_NODES * 64;
    int* bucket_col = (int*)(KVC + (size_t)N_NODES * 128);   // 256B rows
    int* counts  = bucket_col + NE;
    int* offsets = counts + N_NODES;
    int* bsums   = offsets + N_NODES + 1;
    float* wsum  = (float*)(bsums + 256);
    float* S     = wsum + N_NODES;

    float* out_x = out;
    float* out_c = out + (size_t)N_NODES * DIM;

    // CSR build (row-bucketed column list), row-group-partitioned scatter
    (void)hipMemsetAsync(counts, 0, (size_t)N_NODES * sizeof(int), stream);
    k_hist  <<<NFILL_GRID, 256, 0, stream>>>(eidx, counts);
    k_scan1 <<<NSCAN_BLOCKS, 256, 0, stream>>>(counts, offsets, bsums);
    k_scan23<<<NSCAN_BLOCKS, 256, 0, stream>>>(offsets, counts, bsums);
    k_fill  <<<NFILL_GRID, 256, 0, stream>>>(eidx, counts, bucket_col);

    // node projections + packing (Q/K f16, V/C fp8 dword-interleaved)
    k_qkv<<<(N_NODES + 31) / 32, 256, 0, stream>>>(
        x, coord, Wq, bq, Wk, bk, Wv, bv, Qh, KVC);

    // fused edge pass (quarter-per-edge, 4x unrolled), acc -> d_out
    k_edge_fused<<<(N_NODES * 64 + 255) / 256, 256, 0, stream>>>(
        bucket_col, offsets, Qh, KVC, coord, Wc, bc, out_x, out_c, wsum);

    // deterministic global sum, then normalize + residual
    k_redsum<<<1, 1024, 0, stream>>>(wsum, S);
    k_finalize<<<(2 * N_NODES * DIM / 4 + 255) / 256, 256, 0, stream>>>(
        x, coord, S, out);
}

// Round 18
// 198.529 us; speedup vs baseline: 1.0756x; 1.0756x over previous
//
#include <hip/hip_runtime.h>
#include <math.h>

#define N_NODES 50000
#define DIM 64
#define NE 800000
#define NSCAN_BLOCKS ((N_NODES + 255) / 256)   // 196
#define NGROUPS 8                               // row-groups ~ XCDs
#define ROWS_PER_GROUP ((N_NODES + NGROUPS - 1) / NGROUPS)   // 6250
#define NFILL_GRID (392 * NGROUPS)              // 3136 blocks

static __device__ __forceinline__ unsigned short f2bf(float f) {
    unsigned int u = __float_as_uint(f);
    u += 0x7fffu + ((u >> 16) & 1u);
    return (unsigned short)(u >> 16);
}
static __device__ __forceinline__ float bf2f(unsigned short u) {
    return __uint_as_float(((unsigned int)u) << 16);
}

typedef _Float16 half2v __attribute__((ext_vector_type(2)));
typedef float v2f __attribute__((ext_vector_type(2)));

static __device__ __forceinline__ half2v u2h(unsigned int u) {
    union { unsigned int u; half2v h; } x; x.u = u; return x.h;
}
static __device__ __forceinline__ unsigned short f2h(float f) {
    union { _Float16 h; unsigned short s; } x; x.h = (_Float16)f; return x.s;
}

#if defined(__has_builtin)
#  if __has_builtin(__builtin_amdgcn_fdot2)
#    define HAVE_FDOT2 1
#  endif
#endif

// acc += dot(f16x2, f16x2) — v_dot2_f32_f16 when available
static __device__ __forceinline__ float dot2acc(unsigned int qa,
                                                unsigned int ka, float c) {
#ifdef HAVE_FDOT2
    return __builtin_amdgcn_fdot2(u2h(qa), u2h(ka), c, false);
#else
    half2v q = u2h(qa), k = u2h(ka);
    return c + (float)q.x * (float)k.x + (float)q.y * (float)k.y;
#endif
}

// decode 2 fp8(e4m3) from dword half (HI must be literal)
template <bool HI>
static __device__ __forceinline__ v2f fp8x2(unsigned int u) {
    return __builtin_amdgcn_cvt_pk_f32_fp8((int)u, HI);
}
// pack 4 floats -> 4 fp8 bytes in one dword
static __device__ __forceinline__ unsigned int pack4_fp8(float a, float b,
                                                         float c, float d) {
    int p = __builtin_amdgcn_cvt_pk_fp8_f32(a, b, 0, false);
    p = __builtin_amdgcn_cvt_pk_fp8_f32(c, d, p, true);
    return (unsigned int)p;
}

// ---------------------------------------------------------------------------
// ws layout:
//   Qh   : N*64 ushorts   (f16, pre-scaled by log2(e); wave-uniform read)
//   KVC  : N rows x 256B  (K f16 128B | V,C fp8 dword-interleaved 128B)
//   bucket_col : NE ints
//   counts  : N ints (doubles as fill cursor)
//   offsets : N+1 ints
//   bsums   : 256 ints
//   wsum    : N floats
//   S       : 1 float
// Lessons: single-address f32 atomicAdd @50k waves = 580us serialization
// [R10]; LDS-heavy kernel fused with scatter = occupancy kill [R13];
// sub-dword scatter stores = 16x line write amplification [R13/R14];
// row-group partition makes scatter L2-local (fill 61->~15us) [R15];
// edge kernel latency-limited at VALUBusy~63% [R16]; 4x edge unroll
// regresses via Poisson-degree tail waste (~48% clamped slots) [R17] —
// 2x (8-stride) is the MLP-vs-tail-waste sweet spot.
// ---------------------------------------------------------------------------

// QKV projections: 32 nodes/block, bf16 weights in LDS, 8 nodes/thread.
__global__ __launch_bounds__(256, 5) void k_qkv(
    const float* __restrict__ x, const float* __restrict__ coord,
    const float* __restrict__ Wq, const float* __restrict__ bq,
    const float* __restrict__ Wk, const float* __restrict__ bk,
    const float* __restrict__ Wv, const float* __restrict__ bv,
    unsigned short* __restrict__ Qh, unsigned short* __restrict__ KVC)
{
    __shared__ ushort4 WT2[3][1024];  // 24 KB bf16 weights
    __shared__ float4  xs4[32][16];   // 8 KB (reused as V stage after compute)

    const int tid  = threadIdx.x;
    const int base = blockIdx.x * 32;

    for (int t = tid; t < 1024; t += 256) {
        int d = t & 63, j2 = t >> 6;
        float4 a = ((const float4*)Wq)[d * 16 + j2];
        float4 b = ((const float4*)Wk)[d * 16 + j2];
        float4 c = ((const float4*)Wv)[d * 16 + j2];
        WT2[0][t] = make_ushort4(f2bf(a.x), f2bf(a.y), f2bf(a.z), f2bf(a.w));
        WT2[1][t] = make_ushort4(f2bf(b.x), f2bf(b.y), f2bf(b.z), f2bf(b.w));
        WT2[2][t] = make_ushort4(f2bf(c.x), f2bf(c.y), f2bf(c.z), f2bf(c.w));
    }
    for (int t = tid; t < 512; t += 256) {
        int r = t >> 4, j2 = t & 15;
        if (base + r < N_NODES)
            xs4[r][j2] = ((const float4*)x)[(size_t)(base + r) * 16 + j2];
    }
    __syncthreads();

    const int wv = tid >> 6;
    const int d  = tid & 63;
    const float bqv = bq[d], bkv = bk[d], bvv = bv[d];

    float aq[8], ak[8], av[8];
    #pragma unroll
    for (int r = 0; r < 8; ++r) { aq[r] = bqv; ak[r] = bkv; av[r] = bvv; }

    #pragma unroll 4
    for (int j2 = 0; j2 < 16; ++j2) {
        ushort4 uq = WT2[0][j2 * 64 + d];
        ushort4 uk = WT2[1][j2 * 64 + d];
        ushort4 uv = WT2[2][j2 * 64 + d];
        float wqx = bf2f(uq.x), wqy = bf2f(uq.y), wqz = bf2f(uq.z), wqw = bf2f(uq.w);
        float wkx = bf2f(uk.x), wky = bf2f(uk.y), wkz = bf2f(uk.z), wkw = bf2f(uk.w);
        float wvx = bf2f(uv.x), wvy = bf2f(uv.y), wvz = bf2f(uv.z), wvw = bf2f(uv.w);
        #pragma unroll
        for (int r = 0; r < 8; ++r) {
            float4 xv = xs4[wv * 8 + r][j2];   // wave-uniform broadcast
            aq[r] += xv.x * wqx + xv.y * wqy + xv.z * wqz + xv.w * wqw;
            ak[r] += xv.x * wkx + xv.y * wky + xv.z * wkz + xv.w * wkw;
            av[r] += xv.x * wvx + xv.y * wvy + xv.z * wvz + xv.w * wvw;
        }
    }
    // Q (f16, pre-scaled by log2e) and K (f16) stores: coalesced 128B/wave
    #pragma unroll
    for (int r = 0; r < 8; ++r) {
        int n = base + wv * 8 + r;
        if (n < N_NODES) {
            Qh[(size_t)n * 64 + d]  = f2h(aq[r] * 1.44269504f);
            KVC[(size_t)n * 128 + d] = f2h(ak[r]);
        }
    }
    // V: stage f32 in LDS, then pack {V,C} fp8 dwords -> one uint2 store
    __syncthreads();   // all xs4 reads done
    float* vf = (float*)xs4;
    #pragma unroll
    for (int r = 0; r < 8; ++r)
        vf[(wv * 8 + r) * 64 + d] = av[r];
    __syncthreads();
    uint2* VC2 = (uint2*)KVC;           // row = 32 uint2 (256B)
    for (int t = tid; t < 512; t += 256) {
        int ln = t >> 4, j = t & 15;
        int n = base + ln;
        if (n < N_NODES) {
            float4 vv = ((const float4*)vf)[ln * 16 + j];
            float4 cv = ((const float4*)coord)[(size_t)n * 16 + j];
            uint2 o;
            o.x = pack4_fp8(vv.x, vv.y, vv.z, vv.w);
            o.y = pack4_fp8(cv.x, cv.y, cv.z, cv.w);
            VC2[(size_t)n * 32 + 16 + j] = o;
        }
    }
}

// Row-group-partitioned histogram (group ~ XCD; atomics L2-local)
__global__ __launch_bounds__(256) void k_hist(
    const int* __restrict__ eidx, int* __restrict__ counts)
{
    const int grp = blockIdx.x & (NGROUPS - 1);
    const int blk = blockIdx.x >> 3;
    const int nblk = gridDim.x >> 3;
    const int rlo = grp * ROWS_PER_GROUP;
    const int rhi = rlo + ROWS_PER_GROUP;
    for (int e = blk * 256 + threadIdx.x; e < NE; e += nblk * 256) {
        int r = eidx[e];
        if (r >= rlo && r < rhi) atomicAdd(counts + r, 1);
    }
}

__global__ __launch_bounds__(256) void k_scan1(
    const int* __restrict__ counts, int* __restrict__ offsets,
    int* __restrict__ bsums)
{
    __shared__ int tmp[256];
    int i = blockIdx.x * 256 + threadIdx.x;
    int v = (i < N_NODES) ? counts[i] : 0;
    tmp[threadIdx.x] = v;
    __syncthreads();
    #pragma unroll
    for (int off = 1; off < 256; off <<= 1) {
        int t = (threadIdx.x >= off) ? tmp[threadIdx.x - off] : 0;
        __syncthreads();
        tmp[threadIdx.x] += t;
        __syncthreads();
    }
    if (i < N_NODES) offsets[i] = tmp[threadIdx.x] - v;   // exclusive
    if (threadIdx.x == 255) bsums[blockIdx.x] = tmp[255];
}

// merged scan2+scan3
__global__ __launch_bounds__(256) void k_scan23(
    int* __restrict__ offsets, int* __restrict__ counts,
    const int* __restrict__ bsums)
{
    __shared__ int red[4];
    const int tid = threadIdx.x;
    const int b   = blockIdx.x;
    int v = (tid < b && tid < NSCAN_BLOCKS) ? bsums[tid] : 0;
    #pragma unroll
    for (int off = 32; off; off >>= 1) v += __shfl_xor(v, off);
    if ((tid & 63) == 0) red[tid >> 6] = v;
    __syncthreads();
    const int pre = red[0] + red[1] + red[2] + red[3];

    int i = b * 256 + tid;
    if (i < N_NODES) {
        int o = offsets[i] + pre;
        offsets[i] = o;
        counts[i]  = o;     // cursor for fill
    }
    if (i == 0) offsets[N_NODES] = NE;
}

// Row-group-partitioned fill (writes L2-local -> no 16x amplification)
__global__ __launch_bounds__(256) void k_fill(
    const int* __restrict__ eidx, int* __restrict__ cursor,
    int* __restrict__ bucket_col)
{
    const int grp = blockIdx.x & (NGROUPS - 1);
    const int blk = blockIdx.x >> 3;
    const int nblk = gridDim.x >> 3;
    const int rlo = grp * ROWS_PER_GROUP;
    const int rhi = rlo + ROWS_PER_GROUP;
    const int* __restrict__ cols = eidx + NE;
    for (int e = blk * 256 + threadIdx.x; e < NE; e += nblk * 256) {
        int r = eidx[e];
        if (r >= rlo && r < rhi) {
            int pos = atomicAdd(cursor + r, 1);
            bucket_col[pos] = cols[e];
        }
    }
}

// Fused edge pass: wave per node, 16-lane quarter per edge, lane = 4 dims,
// 2x unrolled (8-stride: MLP-vs-Poisson-tail sweet spot [R17]).
// K f16 (fdot2), V/C fp8 (one uint2 load), 2 lines/neighbor.
__global__ __launch_bounds__(256) void k_edge_fused(
    const int* __restrict__ bucket_col, const int* __restrict__ offsets,
    const unsigned short* __restrict__ Qh, const unsigned short* __restrict__ KVC,
    const float* __restrict__ coord,
    const float* __restrict__ Wc, const float* __restrict__ bc,
    float* __restrict__ out_x, float* __restrict__ out_c,
    float* __restrict__ wsum)
{
    const int lane = threadIdx.x & 63;
    const int n = (blockIdx.x * 256 + threadIdx.x) >> 6;
    if (n >= N_NODES) return;
    const int qt = lane >> 4;          // quarter: which edge of the group of 4
    const int sl = lane & 15;          // dim-quad slot (dims 4sl..4sl+3)

    const uint2 q2   = ((const uint2*)Qh)[(size_t)n * 16 + sl];   // 2x f16x2
    const float4 cr4 = ((const float4*)coord)[(size_t)n * 16 + sl];
    const float4 wc4 = ((const float4*)Wc)[sl];
    const float4 bc4 = ((const float4*)bc)[sl];
    const uint2* K2  = (const uint2*)KVC;    // K: idx c*32 + sl
    const uint2* VC2 = (const uint2*)KVC;    // VC: idx c*32 + 16 + sl

    const int s = offsets[n], t = offsets[n + 1];
    float4 accx = {0.f, 0.f, 0.f, 0.f};
    float4 accc = {0.f, 0.f, 0.f, 0.f};
    float psum = 0.0f;

    for (int base = s; base < t; base += 8) {
        int pos0 = base + qt;
        int pos1 = base + 4 + qt;
        bool v0 = pos0 < t, v1 = pos1 < t;
        int c0 = bucket_col[v0 ? pos0 : (t - 1)];
        int c1 = bucket_col[v1 ? pos1 : (t - 1)];
        uint2 k0  = K2[(size_t)c0 * 32 + sl];
        uint2 vc0 = VC2[(size_t)c0 * 32 + 16 + sl];
        uint2 k1  = K2[(size_t)c1 * 32 + sl];
        uint2 vc1 = VC2[(size_t)c1 * 32 + 16 + sl];

        v2f c0a = fp8x2<false>(vc0.y), c0b = fp8x2<true>(vc0.y);
        v2f c1a = fp8x2<false>(vc1.y), c1b = fp8x2<true>(vc1.y);

        // logits via f16 dot2 (Q pre-scaled by log2e -> exp2 later)
        float d0 = dot2acc(q2.y, k0.y, dot2acc(q2.x, k0.x, 0.0f));
        float d1 = dot2acc(q2.y, k1.y, dot2acc(q2.x, k1.x, 0.0f));

        float dx0x = cr4.x - c0a.x, dx0y = cr4.y - c0a.y;
        float dx0z = cr4.z - c0b.x, dx0w = cr4.w - c0b.y;
        float e0 = dx0x * dx0x + dx0y * dx0y + dx0z * dx0z + dx0w * dx0w;
        float dx1x = cr4.x - c1a.x, dx1y = cr4.y - c1a.y;
        float dx1z = cr4.z - c1b.x, dx1w = cr4.w - c1b.y;
        float e1 = dx1x * dx1x + dx1y * dx1y + dx1z * dx1z + dx1w * dx1w;

        #pragma unroll
        for (int off = 1; off <= 8; off <<= 1) {   // reduce within quarter
            d0 += __shfl_xor(d0, off);
            e0 += __shfl_xor(e0, off);
            d1 += __shfl_xor(d1, off);
            e1 += __shfl_xor(e1, off);
        }
        float p0e = v0 ? exp2f(d0) : 0.0f;
        float p1e = v1 ? exp2f(d1) : 0.0f;
        float dist0 = sqrtf(e0), dist1 = sqrtf(e1);
        psum += p0e + p1e;

        v2f v0a = fp8x2<false>(vc0.x), v0b = fp8x2<true>(vc0.x);
        v2f v1a = fp8x2<false>(vc1.x), v1b = fp8x2<true>(vc1.x);
        accx.x += p0e * v0a.x + p1e * v1a.x;
        accx.y += p0e * v0a.y + p1e * v1a.y;
        accx.z += p0e * v0b.x + p1e * v1b.x;
        accx.w += p0e * v0b.y + p1e * v1b.y;
        accc.x += p0e * (dist0 * wc4.x + bc4.x) * dx0x
                + p1e * (dist1 * wc4.x + bc4.x) * dx1x;
        accc.y += p0e * (dist0 * wc4.y + bc4.y) * dx0y
                + p1e * (dist1 * wc4.y + bc4.y) * dx1y;
        accc.z += p0e * (dist0 * wc4.z + bc4.z) * dx0z
                + p1e * (dist1 * wc4.z + bc4.z) * dx1z;
        accc.w += p0e * (dist0 * wc4.w + bc4.w) * dx0w
                + p1e * (dist1 * wc4.w + bc4.w) * dx1w;
    }

    // cross-quarter combine (once per node)
    #pragma unroll
    for (int off = 16; off <= 32; off <<= 1) {
        accx.x += __shfl_xor(accx.x, off);
        accx.y += __shfl_xor(accx.y, off);
        accx.z += __shfl_xor(accx.z, off);
        accx.w += __shfl_xor(accx.w, off);
        accc.x += __shfl_xor(accc.x, off);
        accc.y += __shfl_xor(accc.y, off);
        accc.z += __shfl_xor(accc.z, off);
        accc.w += __shfl_xor(accc.w, off);
        psum   += __shfl_xor(psum, off);
    }
    if (lane < 16) {
        ((float4*)out_x)[(size_t)n * 16 + sl] = accx;   // unnormalized
        ((float4*)out_c)[(size_t)n * 16 + sl] = accc;
    }
    if (lane == 0) wsum[n] = psum;
}

// deterministic fixed-tree reduction of wsum -> S (single block)
__global__ __launch_bounds__(1024) void k_redsum(
    const float* __restrict__ wsum, float* __restrict__ S)
{
    __shared__ float red[16];
    float a = 0.0f;
    for (int i = threadIdx.x; i < N_NODES; i += 1024) a += wsum[i];
    #pragma unroll
    for (int off = 32; off; off >>= 1) a += __shfl_xor(a, off);
    if ((threadIdx.x & 63) == 0) red[threadIdx.x >> 6] = a;
    __syncthreads();
    if (threadIdx.x == 0) {
        float s = 0.0f;
        #pragma unroll
        for (int w = 0; w < 16; ++w) s += red[w];
        *S = s;
    }
}

// out = residual + out * (1/S), one float4 per thread
__global__ __launch_bounds__(256) void k_finalize(
    const float* __restrict__ x, const float* __restrict__ coord,
    const float* __restrict__ S, float* __restrict__ out)
{
    const float inv = 1.0f / *S;
    const int nd4 = (N_NODES * DIM) / 4;      // 800000
    const float4* x4 = (const float4*)x;
    const float4* c4 = (const float4*)coord;
    float4* o4 = (float4*)out;
    int i = blockIdx.x * 256 + threadIdx.x;
    if (i < 2 * nd4) {
        float4 r = (i < nd4) ? x4[i] : c4[i - nd4];
        float4 a = o4[i];
        a.x = r.x + a.x * inv;
        a.y = r.y + a.y * inv;
        a.z = r.z + a.z * inv;
        a.w = r.w + a.w * inv;
        o4[i] = a;
    }
}

extern "C" void kernel_launch(void* const* d_in, const int* in_sizes, int n_in,
                              void* d_out, int out_size, void* d_ws, size_t ws_size,
                              hipStream_t stream)
{
    const float* x     = (const float*)d_in[0];
    const float* coord = (const float*)d_in[1];
    const float* Wq    = (const float*)d_in[2];
    const float* bq    = (const float*)d_in[3];
    const float* Wk    = (const float*)d_in[4];
    const float* bk    = (const float*)d_in[5];
    const float* Wv    = (const float*)d_in[6];
    const float* bv    = (const float*)d_in[7];
    const float* Wc    = (const float*)d_in[8];
    const float* bc    = (const float*)d_in[9];
    const int*   eidx  = (const int*)d_in[10];

    float* out = (float*)d_out;
    float* ws  = (float*)d_ws;

    unsigned short* Qh  = (unsigned short*)ws;
    unsigned short* KVC = Qh + (size_t)N_NODES * 64;
    int* bucket_col = (int*)(KVC + (size_t)N_NODES * 128);   // 256B rows
    int* counts  = bucket_col + NE;
    int* offsets = counts + N_NODES;
    int* bsums   = offsets + N_NODES + 1;
    float* wsum  = (float*)(bsums + 256);
    float* S     = wsum + N_NODES;

    float* out_x = out;
    float* out_c = out + (size_t)N_NODES * DIM;

    // CSR build (row-bucketed column list), row-group-partitioned scatter
    (void)hipMemsetAsync(counts, 0, (size_t)N_NODES * sizeof(int), stream);
    k_hist  <<<NFILL_GRID, 256, 0, stream>>>(eidx, counts);
    k_scan1 <<<NSCAN_BLOCKS, 256, 0, stream>>>(counts, offsets, bsums);
    k_scan23<<<NSCAN_BLOCKS, 256, 0, stream>>>(offsets, counts, bsums);
    k_fill  <<<NFILL_GRID, 256, 0, stream>>>(eidx, counts, bucket_col);

    // node projections + packing (Q/K f16, V/C fp8 dword-interleaved)
    k_qkv<<<(N_NODES + 31) / 32, 256, 0, stream>>>(
        x, coord, Wq, bq, Wk, bk, Wv, bv, Qh, KVC);

    // fused edge pass (quarter-per-edge, 2x unrolled), acc -> d_out
    k_edge_fused<<<(N_NODES * 64 + 255) / 256, 256, 0, stream>>>(
        bucket_col, offsets, Qh, KVC, coord, Wc, bc, out_x, out_c, wsum);

    // deterministic global sum, then normalize + residual
    k_redsum<<<1, 1024, 0, stream>>>(wsum, S);
    k_finalize<<<(2 * N_NODES * DIM / 4 + 255) / 256, 256, 0, stream>>>(
        x, coord, S, out);
}

// Round 19
// 187.360 us; speedup vs baseline: 1.1397x; 1.0596x over previous
//
#include <hip/hip_runtime.h>
#include <math.h>

#define N_NODES 50000
#define DIM 64
#define NE 800000
#define NSCAN_BLOCKS ((N_NODES + 255) / 256)   // 196
#define NGROUPS 8                               // row-groups ~ XCDs
#define ROWS_PER_GROUP ((N_NODES + NGROUPS - 1) / NGROUPS)   // 6250
#define NFILL_GRID (392 * NGROUPS)              // 3136 blocks

static __device__ __forceinline__ unsigned short f2bf(float f) {
    unsigned int u = __float_as_uint(f);
    u += 0x7fffu + ((u >> 16) & 1u);
    return (unsigned short)(u >> 16);
}

typedef _Float16 half2v __attribute__((ext_vector_type(2)));
typedef float v2f __attribute__((ext_vector_type(2)));

static __device__ __forceinline__ half2v u2h(unsigned int u) {
    union { unsigned int u; half2v h; } x; x.u = u; return x.h;
}
static __device__ __forceinline__ unsigned int h2u(half2v h) {
    union { half2v h; unsigned int u; } x; x.h = h; return x.u;
}
static __device__ __forceinline__ unsigned short f2h(float f) {
    union { _Float16 h; unsigned short s; } x; x.h = (_Float16)f; return x.s;
}
// pack two floats -> f16x2 dword
static __device__ __forceinline__ unsigned int pkh(float a, float b) {
    return (unsigned int)f2h(a) | ((unsigned int)f2h(b) << 16);
}

#if defined(__has_builtin)
#  if __has_builtin(__builtin_amdgcn_fdot2)
#    define HAVE_FDOT2 1
#  endif
#endif

// acc += dot(f16x2, f16x2) — v_dot2_f32_f16 when available
static __device__ __forceinline__ float dot2acc(unsigned int qa,
                                                unsigned int ka, float c) {
#ifdef HAVE_FDOT2
    return __builtin_amdgcn_fdot2(u2h(qa), u2h(ka), c, false);
#else
    half2v q = u2h(qa), k = u2h(ka);
    return c + (float)q.x * (float)k.x + (float)q.y * (float)k.y;
#endif
}

// decode 2 fp8(e4m3) from dword half (HI must be literal)
template <bool HI>
static __device__ __forceinline__ v2f fp8x2(unsigned int u) {
    return __builtin_amdgcn_cvt_pk_f32_fp8((int)u, HI);
}
// pack 4 floats -> 4 fp8 bytes in one dword
static __device__ __forceinline__ unsigned int pack4_fp8(float a, float b,
                                                         float c, float d) {
    int p = __builtin_amdgcn_cvt_pk_fp8_f32(a, b, 0, false);
    p = __builtin_amdgcn_cvt_pk_fp8_f32(c, d, p, true);
    return (unsigned int)p;
}

// ---------------------------------------------------------------------------
// ws layout:
//   Qh   : N*64 ushorts   (f16, pre-scaled by log2(e); wave-uniform read)
//   KVC  : N rows x 256B  (K f16 128B | V,C fp8 dword-interleaved 128B)
//   bucket_col : NE ints
//   counts  : N ints (doubles as fill cursor)
//   offsets : N+1 ints
//   bsums   : 256 ints
//   wsum    : N floats
//   S       : 1 float
// Lessons: single-address f32 atomicAdd @50k waves = 580us serialization
// [R10]; LDS-heavy kernel fused with scatter = occupancy kill [R13];
// sub-dword scatter stores = 16x line write amplification [R13/R14];
// row-group partition makes scatter L2-local (fill 61->~15us) [R15];
// edge kernel latency-limited at VALUBusy~63% [R16]; 4x edge unroll
// regresses via Poisson-tail waste [R17] — 2x is the sweet spot.
// ---------------------------------------------------------------------------

// QKV projections: 32 nodes/block, f16 weights + packed f16x2 FMA
// (v_pk_fma_f16 halves the MAC instruction count; Q/K are f16 and V is
// fp8 downstream, so f16 accumulation is within budget).
__global__ __launch_bounds__(256, 5) void k_qkv(
    const float* __restrict__ x, const float* __restrict__ coord,
    const float* __restrict__ Wq, const float* __restrict__ bq,
    const float* __restrict__ Wk, const float* __restrict__ bk,
    const float* __restrict__ Wv, const float* __restrict__ bv,
    unsigned short* __restrict__ Qh, unsigned short* __restrict__ KVC)
{
    __shared__ uint2 WT[3][1024];   // 24 KB: [m][j2*64+d] = f16 W[d][4j2..]
    __shared__ uint2 xs2[32][16];   // 4 KB: f16 pairs of x (V stage after)

    const int tid  = threadIdx.x;
    const int base = blockIdx.x * 32;

    for (int t = tid; t < 1024; t += 256) {
        int d = t & 63, j2 = t >> 6;
        float4 a = ((const float4*)Wq)[d * 16 + j2];
        float4 b = ((const float4*)Wk)[d * 16 + j2];
        float4 c = ((const float4*)Wv)[d * 16 + j2];
        WT[0][t] = make_uint2(pkh(a.x, a.y), pkh(a.z, a.w));
        WT[1][t] = make_uint2(pkh(b.x, b.y), pkh(b.z, b.w));
        WT[2][t] = make_uint2(pkh(c.x, c.y), pkh(c.z, c.w));
    }
    for (int t = tid; t < 512; t += 256) {
        int r = t >> 4, j2 = t & 15;
        if (base + r < N_NODES) {
            float4 xv = ((const float4*)x)[(size_t)(base + r) * 16 + j2];
            xs2[r][j2] = make_uint2(pkh(xv.x, xv.y), pkh(xv.z, xv.w));
        }
    }
    __syncthreads();

    const int wv = tid >> 6;
    const int d  = tid & 63;
    const float bqv = bq[d], bkv = bk[d], bvv = bv[d];

    half2v aq[8], ak[8], av[8];
    #pragma unroll
    for (int r = 0; r < 8; ++r) {
        aq[r] = (half2v)0; ak[r] = (half2v)0; av[r] = (half2v)0;
    }

    #pragma unroll 4
    for (int j2 = 0; j2 < 16; ++j2) {
        uint2 wq = WT[0][j2 * 64 + d];
        uint2 wk = WT[1][j2 * 64 + d];
        uint2 wvv = WT[2][j2 * 64 + d];
        half2v wq0 = u2h(wq.x), wq1 = u2h(wq.y);
        half2v wk0 = u2h(wk.x), wk1 = u2h(wk.y);
        half2v wv0 = u2h(wvv.x), wv1 = u2h(wvv.y);
        #pragma unroll
        for (int r = 0; r < 8; ++r) {
            uint2 xv = xs2[wv * 8 + r][j2];   // wave-uniform b64 broadcast
            half2v x0 = u2h(xv.x), x1 = u2h(xv.y);
            aq[r] = x0 * wq0 + (x1 * wq1 + aq[r]);   // 2x v_pk_fma_f16
            ak[r] = x0 * wk0 + (x1 * wk1 + ak[r]);
            av[r] = x0 * wv0 + (x1 * wv1 + av[r]);
        }
    }
    // Q (f16, pre-scaled by log2e) and K (f16) stores: coalesced 128B/wave
    float avf[8];
    #pragma unroll
    for (int r = 0; r < 8; ++r) {
        int n = base + wv * 8 + r;
        float q = (float)aq[r].x + (float)aq[r].y + bqv;
        float k = (float)ak[r].x + (float)ak[r].y + bkv;
        avf[r]  = (float)av[r].x + (float)av[r].y + bvv;
        if (n < N_NODES) {
            Qh[(size_t)n * 64 + d]  = f2h(q * 1.44269504f);
            KVC[(size_t)n * 128 + d] = f2h(k);
        }
    }
    // V: stage f16 pairs in xs2 (reuse), repack {V,C} fp8 -> uint2 stores
    __syncthreads();   // all xs2 reads done
    unsigned int* vstage = (unsigned int*)xs2;   // [32 nodes][32 pairs]
    #pragma unroll
    for (int r = 0; r < 4; ++r)   // 8 node-slots = 4 pair-writes per thread?
        ;                          // (packed below: 1 dword per 2 dims)
    #pragma unroll
    for (int r = 0; r < 8; ++r) {
        // pair slot: node (wv*8+r), dims (2*(d>>1)) — write one dword per
        // even lane pair is racy; instead each thread writes its own dim
        // as half of a pair via 16-bit halves packed by parity of d:
        ((unsigned short*)vstage)[(wv * 8 + r) * 64 + d] = f2h(avf[r]);
    }
    __syncthreads();
    uint2* VC2 = (uint2*)KVC;           // row = 32 uint2 (256B)
    for (int t = tid; t < 512; t += 256) {
        int ln = t >> 4, j = t & 15;
        int n = base + ln;
        if (n < N_NODES) {
            // read 4 f16 dims of V from stage
            uint2 vp = ((const uint2*)vstage)[ln * 16 + j];
            half2v v0 = u2h(vp.x), v1 = u2h(vp.y);
            float4 cv = ((const float4*)coord)[(size_t)n * 16 + j];
            uint2 o;
            o.x = pack4_fp8((float)v0.x, (float)v0.y,
                            (float)v1.x, (float)v1.y);
            o.y = pack4_fp8(cv.x, cv.y, cv.z, cv.w);
            VC2[(size_t)n * 32 + 16 + j] = o;
        }
    }
}

// Row-group-partitioned histogram (group ~ XCD; atomics L2-local)
__global__ __launch_bounds__(256) void k_hist(
    const int* __restrict__ eidx, int* __restrict__ counts)
{
    const int grp = blockIdx.x & (NGROUPS - 1);
    const int blk = blockIdx.x >> 3;
    const int nblk = gridDim.x >> 3;
    const int rlo = grp * ROWS_PER_GROUP;
    const int rhi = rlo + ROWS_PER_GROUP;
    for (int e = blk * 256 + threadIdx.x; e < NE; e += nblk * 256) {
        int r = eidx[e];
        if (r >= rlo && r < rhi) atomicAdd(counts + r, 1);
    }
}

__global__ __launch_bounds__(256) void k_scan1(
    const int* __restrict__ counts, int* __restrict__ offsets,
    int* __restrict__ bsums)
{
    __shared__ int tmp[256];
    int i = blockIdx.x * 256 + threadIdx.x;
    int v = (i < N_NODES) ? counts[i] : 0;
    tmp[threadIdx.x] = v;
    __syncthreads();
    #pragma unroll
    for (int off = 1; off < 256; off <<= 1) {
        int t = (threadIdx.x >= off) ? tmp[threadIdx.x - off] : 0;
        __syncthreads();
        tmp[threadIdx.x] += t;
        __syncthreads();
    }
    if (i < N_NODES) offsets[i] = tmp[threadIdx.x] - v;   // exclusive
    if (threadIdx.x == 255) bsums[blockIdx.x] = tmp[255];
}

// merged scan2+scan3
__global__ __launch_bounds__(256) void k_scan23(
    int* __restrict__ offsets, int* __restrict__ counts,
    const int* __restrict__ bsums)
{
    __shared__ int red[4];
    const int tid = threadIdx.x;
    const int b   = blockIdx.x;
    int v = (tid < b && tid < NSCAN_BLOCKS) ? bsums[tid] : 0;
    #pragma unroll
    for (int off = 32; off; off >>= 1) v += __shfl_xor(v, off);
    if ((tid & 63) == 0) red[tid >> 6] = v;
    __syncthreads();
    const int pre = red[0] + red[1] + red[2] + red[3];

    int i = b * 256 + tid;
    if (i < N_NODES) {
        int o = offsets[i] + pre;
        offsets[i] = o;
        counts[i]  = o;     // cursor for fill
    }
    if (i == 0) offsets[N_NODES] = NE;
}

// Row-group-partitioned fill (writes L2-local -> no 16x amplification)
__global__ __launch_bounds__(256) void k_fill(
    const int* __restrict__ eidx, int* __restrict__ cursor,
    int* __restrict__ bucket_col)
{
    const int grp = blockIdx.x & (NGROUPS - 1);
    const int blk = blockIdx.x >> 3;
    const int nblk = gridDim.x >> 3;
    const int rlo = grp * ROWS_PER_GROUP;
    const int rhi = rlo + ROWS_PER_GROUP;
    const int* __restrict__ cols = eidx + NE;
    for (int e = blk * 256 + threadIdx.x; e < NE; e += nblk * 256) {
        int r = eidx[e];
        if (r >= rlo && r < rhi) {
            int pos = atomicAdd(cursor + r, 1);
            bucket_col[pos] = cols[e];
        }
    }
}

// Fused edge pass: wave per node, 16-lane quarter per edge, lane = 4 dims,
// 2x unrolled (8-stride: MLP-vs-Poisson-tail sweet spot [R17]).
// K f16 (fdot2), V/C fp8 (one uint2 load), 2 lines/neighbor.
__global__ __launch_bounds__(256) void k_edge_fused(
    const int* __restrict__ bucket_col, const int* __restrict__ offsets,
    const unsigned short* __restrict__ Qh, const unsigned short* __restrict__ KVC,
    const float* __restrict__ coord,
    const float* __restrict__ Wc, const float* __restrict__ bc,
    float* __restrict__ out_x, float* __restrict__ out_c,
    float* __restrict__ wsum)
{
    const int lane = threadIdx.x & 63;
    const int n = (blockIdx.x * 256 + threadIdx.x) >> 6;
    if (n >= N_NODES) return;
    const int qt = lane >> 4;          // quarter: which edge of the group of 4
    const int sl = lane & 15;          // dim-quad slot (dims 4sl..4sl+3)

    const uint2 q2   = ((const uint2*)Qh)[(size_t)n * 16 + sl];   // 2x f16x2
    const float4 cr4 = ((const float4*)coord)[(size_t)n * 16 + sl];
    const float4 wc4 = ((const float4*)Wc)[sl];
    const float4 bc4 = ((const float4*)bc)[sl];
    const uint2* K2  = (const uint2*)KVC;    // K: idx c*32 + sl
    const uint2* VC2 = (const uint2*)KVC;    // VC: idx c*32 + 16 + sl

    const int s = offsets[n], t = offsets[n + 1];
    float4 accx = {0.f, 0.f, 0.f, 0.f};
    float4 accc = {0.f, 0.f, 0.f, 0.f};
    float psum = 0.0f;

    for (int base = s; base < t; base += 8) {
        int pos0 = base + qt;
        int pos1 = base + 4 + qt;
        bool v0 = pos0 < t, v1 = pos1 < t;
        int c0 = bucket_col[v0 ? pos0 : (t - 1)];
        int c1 = bucket_col[v1 ? pos1 : (t - 1)];
        uint2 k0  = K2[(size_t)c0 * 32 + sl];
        uint2 vc0 = VC2[(size_t)c0 * 32 + 16 + sl];
        uint2 k1  = K2[(size_t)c1 * 32 + sl];
        uint2 vc1 = VC2[(size_t)c1 * 32 + 16 + sl];

        v2f c0a = fp8x2<false>(vc0.y), c0b = fp8x2<true>(vc0.y);
        v2f c1a = fp8x2<false>(vc1.y), c1b = fp8x2<true>(vc1.y);

        // logits via f16 dot2 (Q pre-scaled by log2e -> exp2 later)
        float d0 = dot2acc(q2.y, k0.y, dot2acc(q2.x, k0.x, 0.0f));
        float d1 = dot2acc(q2.y, k1.y, dot2acc(q2.x, k1.x, 0.0f));

        float dx0x = cr4.x - c0a.x, dx0y = cr4.y - c0a.y;
        float dx0z = cr4.z - c0b.x, dx0w = cr4.w - c0b.y;
        float e0 = dx0x * dx0x + dx0y * dx0y + dx0z * dx0z + dx0w * dx0w;
        float dx1x = cr4.x - c1a.x, dx1y = cr4.y - c1a.y;
        float dx1z = cr4.z - c1b.x, dx1w = cr4.w - c1b.y;
        float e1 = dx1x * dx1x + dx1y * dx1y + dx1z * dx1z + dx1w * dx1w;

        #pragma unroll
        for (int off = 1; off <= 8; off <<= 1) {   // reduce within quarter
            d0 += __shfl_xor(d0, off);
            e0 += __shfl_xor(e0, off);
            d1 += __shfl_xor(d1, off);
            e1 += __shfl_xor(e1, off);
        }
        float p0e = v0 ? exp2f(d0) : 0.0f;
        float p1e = v1 ? exp2f(d1) : 0.0f;
        float dist0 = sqrtf(e0), dist1 = sqrtf(e1);
        psum += p0e + p1e;

        v2f v0a = fp8x2<false>(vc0.x), v0b = fp8x2<true>(vc0.x);
        v2f v1a = fp8x2<false>(vc1.x), v1b = fp8x2<true>(vc1.x);
        accx.x += p0e * v0a.x + p1e * v1a.x;
        accx.y += p0e * v0a.y + p1e * v1a.y;
        accx.z += p0e * v0b.x + p1e * v1b.x;
        accx.w += p0e * v0b.y + p1e * v1b.y;
        accc.x += p0e * (dist0 * wc4.x + bc4.x) * dx0x
                + p1e * (dist1 * wc4.x + bc4.x) * dx1x;
        accc.y += p0e * (dist0 * wc4.y + bc4.y) * dx0y
                + p1e * (dist1 * wc4.y + bc4.y) * dx1y;
        accc.z += p0e * (dist0 * wc4.z + bc4.z) * dx0z
                + p1e * (dist1 * wc4.z + bc4.z) * dx1z;
        accc.w += p0e * (dist0 * wc4.w + bc4.w) * dx0w
                + p1e * (dist1 * wc4.w + bc4.w) * dx1w;
    }

    // cross-quarter combine (once per node)
    #pragma unroll
    for (int off = 16; off <= 32; off <<= 1) {
        accx.x += __shfl_xor(accx.x, off);
        accx.y += __shfl_xor(accx.y, off);
        accx.z += __shfl_xor(accx.z, off);
        accx.w += __shfl_xor(accx.w, off);
        accc.x += __shfl_xor(accc.x, off);
        accc.y += __shfl_xor(accc.y, off);
        accc.z += __shfl_xor(accc.z, off);
        accc.w += __shfl_xor(accc.w, off);
        psum   += __shfl_xor(psum, off);
    }
    if (lane < 16) {
        ((float4*)out_x)[(size_t)n * 16 + sl] = accx;   // unnormalized
        ((float4*)out_c)[(size_t)n * 16 + sl] = accc;
    }
    if (lane == 0) wsum[n] = psum;
}

// deterministic fixed-tree reduction of wsum -> S (single block)
__global__ __launch_bounds__(1024) void k_redsum(
    const float* __restrict__ wsum, float* __restrict__ S)
{
    __shared__ float red[16];
    float a = 0.0f;
    for (int i = threadIdx.x; i < N_NODES; i += 1024) a += wsum[i];
    #pragma unroll
    for (int off = 32; off; off >>= 1) a += __shfl_xor(a, off);
    if ((threadIdx.x & 63) == 0) red[threadIdx.x >> 6] = a;
    __syncthreads();
    if (threadIdx.x == 0) {
        float s = 0.0f;
        #pragma unroll
        for (int w = 0; w < 16; ++w) s += red[w];
        *S = s;
    }
}

// out = residual + out * (1/S), one float4 per thread
__global__ __launch_bounds__(256) void k_finalize(
    const float* __restrict__ x, const float* __restrict__ coord,
    const float* __restrict__ S, float* __restrict__ out)
{
    const float inv = 1.0f / *S;
    const int nd4 = (N_NODES * DIM) / 4;      // 800000
    const float4* x4 = (const float4*)x;
    const float4* c4 = (const float4*)coord;
    float4* o4 = (float4*)out;
    int i = blockIdx.x * 256 + threadIdx.x;
    if (i < 2 * nd4) {
        float4 r = (i < nd4) ? x4[i] : c4[i - nd4];
        float4 a = o4[i];
        a.x = r.x + a.x * inv;
        a.y = r.y + a.y * inv;
        a.z = r.z + a.z * inv;
        a.w = r.w + a.w * inv;
        o4[i] = a;
    }
}

extern "C" void kernel_launch(void* const* d_in, const int* in_sizes, int n_in,
                              void* d_out, int out_size, void* d_ws, size_t ws_size,
                              hipStream_t stream)
{
    const float* x     = (const float*)d_in[0];
    const float* coord = (const float*)d_in[1];
    const float* Wq    = (const float*)d_in[2];
    const float* bq    = (const float*)d_in[3];
    const float* Wk    = (const float*)d_in[4];
    const float* bk    = (const float*)d_in[5];
    const float* Wv    = (const float*)d_in[6];
    const float* bv    = (const float*)d_in[7];
    const float* Wc    = (const float*)d_in[8];
    const float* bc    = (const float*)d_in[9];
    const int*   eidx  = (const int*)d_in[10];

    float* out = (float*)d_out;
    float* ws  = (float*)d_ws;

    unsigned short* Qh  = (unsigned short*)ws;
    unsigned short* KVC = Qh + (size_t)N_NODES * 64;
    int* bucket_col = (int*)(KVC + (size_t)N_NODES * 128);   // 256B rows
    int* counts  = bucket_col + NE;
    int* offsets = counts + N_NODES;
    int* bsums   = offsets + N_NODES + 1;
    float* wsum  = (float*)(bsums + 256);
    float* S     = wsum + N_NODES;

    float* out_x = out;
    float* out_c = out + (size_t)N_NODES * DIM;

    // CSR build (row-bucketed column list), row-group-partitioned scatter
    (void)hipMemsetAsync(counts, 0, (size_t)N_NODES * sizeof(int), stream);
    k_hist  <<<NFILL_GRID, 256, 0, stream>>>(eidx, counts);
    k_scan1 <<<NSCAN_BLOCKS, 256, 0, stream>>>(counts, offsets, bsums);
    k_scan23<<<NSCAN_BLOCKS, 256, 0, stream>>>(offsets, counts, bsums);
    k_fill  <<<NFILL_GRID, 256, 0, stream>>>(eidx, counts, bucket_col);

    // node projections + packing (packed-f16 FMA; Q/K f16, V/C fp8)
    k_qkv<<<(N_NODES + 31) / 32, 256, 0, stream>>>(
        x, coord, Wq, bq, Wk, bk, Wv, bv, Qh, KVC);

    // fused edge pass (quarter-per-edge, 2x unrolled), acc -> d_out
    k_edge_fused<<<(N_NODES * 64 + 255) / 256, 256, 0, stream>>>(
        bucket_col, offsets, Qh, KVC, coord, Wc, bc, out_x, out_c, wsum);

    // deterministic global sum, then normalize + residual
    k_redsum<<<1, 1024, 0, stream>>>(wsum, S);
    k_finalize<<<(2 * N_NODES * DIM / 4 + 255) / 256, 256, 0, stream>>>(
        x, coord, S, out);
}

// Round 20
// 183.396 us; speedup vs baseline: 1.1644x; 1.0216x over previous
//
#include <hip/hip_runtime.h>
#include <math.h>

#define N_NODES 50000
#define DIM 64
#define NE 800000
#define NSCAN_BLOCKS ((N_NODES + 255) / 256)   // 196
#define NGROUPS 8                               // row-groups ~ XCDs
#define ROWS_PER_GROUP ((N_NODES + NGROUPS - 1) / NGROUPS)   // 6250
#define NFILL_GRID (392 * NGROUPS)              // 3136 blocks

static __device__ __forceinline__ unsigned short f2bf(float f) {
    unsigned int u = __float_as_uint(f);
    u += 0x7fffu + ((u >> 16) & 1u);
    return (unsigned short)(u >> 16);
}

typedef _Float16 half2v __attribute__((ext_vector_type(2)));
typedef float v2f __attribute__((ext_vector_type(2)));

static __device__ __forceinline__ half2v u2h(unsigned int u) {
    union { unsigned int u; half2v h; } x; x.u = u; return x.h;
}
static __device__ __forceinline__ unsigned short f2h(float f) {
    union { _Float16 h; unsigned short s; } x; x.h = (_Float16)f; return x.s;
}
// pack two floats -> f16x2 dword
static __device__ __forceinline__ unsigned int pkh(float a, float b) {
    return (unsigned int)f2h(a) | ((unsigned int)f2h(b) << 16);
}

#if defined(__has_builtin)
#  if __has_builtin(__builtin_amdgcn_fdot2)
#    define HAVE_FDOT2 1
#  endif
#endif

// acc += dot(f16x2, f16x2) — v_dot2_f32_f16 when available
static __device__ __forceinline__ float dot2acc(unsigned int qa,
                                                unsigned int ka, float c) {
#ifdef HAVE_FDOT2
    return __builtin_amdgcn_fdot2(u2h(qa), u2h(ka), c, false);
#else
    half2v q = u2h(qa), k = u2h(ka);
    return c + (float)q.x * (float)k.x + (float)q.y * (float)k.y;
#endif
}

// decode 2 fp8(e4m3) from dword half (HI must be literal)
template <bool HI>
static __device__ __forceinline__ v2f fp8x2(unsigned int u) {
    return __builtin_amdgcn_cvt_pk_f32_fp8((int)u, HI);
}
// pack 4 floats -> 4 fp8 bytes in one dword
static __device__ __forceinline__ unsigned int pack4_fp8(float a, float b,
                                                         float c, float d) {
    int p = __builtin_amdgcn_cvt_pk_fp8_f32(a, b, 0, false);
    p = __builtin_amdgcn_cvt_pk_fp8_f32(c, d, p, true);
    return (unsigned int)p;
}

// ---------------------------------------------------------------------------
// ws layout:
//   Qh   : N*64 ushorts   (f16, pre-scaled by log2(e); wave-uniform read)
//   KVC  : N rows x 256B  (K f16 128B | V,C fp8 dword-interleaved 128B)
//   bucket_col : NE ints
//   counts  : N ints (doubles as fill cursor; zeroed inside k_qkv)
//   offsets : N+1 ints
//   bsums   : 256 ints
//   wsum    : N floats
//   S       : 1 float
// Lessons: single-address f32 atomicAdd @50k waves = 580us serialization
// [R10] (rules out last-block-reduction completion counters too);
// LDS-heavy kernel fused with scatter = occupancy kill [R13]; sub-dword
// scatter stores = 16x line write amplification [R13/R14]; row-group
// partition makes scatter L2-local [R15]; edge kernel latency/VALU/tail
// equilibrium at ~51us [R16-R18]; packed-f16 qkv -11us [R19].
// ---------------------------------------------------------------------------

// QKV projections (runs FIRST; also zeros the histogram counts so the
// separate memset dispatch disappears). 32 nodes/block, f16 weights +
// packed f16x2 FMA.
__global__ __launch_bounds__(256, 5) void k_qkv(
    const float* __restrict__ x, const float* __restrict__ coord,
    const float* __restrict__ Wq, const float* __restrict__ bq,
    const float* __restrict__ Wk, const float* __restrict__ bk,
    const float* __restrict__ Wv, const float* __restrict__ bv,
    unsigned short* __restrict__ Qh, unsigned short* __restrict__ KVC,
    int* __restrict__ counts)
{
    __shared__ uint2 WT[3][1024];   // 24 KB: [m][j2*64+d] = f16 W[d][4j2..]
    __shared__ uint2 xs2[32][16];   // 4 KB: f16 pairs of x (V stage after)

    const int tid  = threadIdx.x;
    const int base = blockIdx.x * 32;

    // zero this block's slice of counts (replaces hipMemsetAsync dispatch)
    if (tid < 32 && base + tid < N_NODES) counts[base + tid] = 0;

    for (int t = tid; t < 1024; t += 256) {
        int d = t & 63, j2 = t >> 6;
        float4 a = ((const float4*)Wq)[d * 16 + j2];
        float4 b = ((const float4*)Wk)[d * 16 + j2];
        float4 c = ((const float4*)Wv)[d * 16 + j2];
        WT[0][t] = make_uint2(pkh(a.x, a.y), pkh(a.z, a.w));
        WT[1][t] = make_uint2(pkh(b.x, b.y), pkh(b.z, b.w));
        WT[2][t] = make_uint2(pkh(c.x, c.y), pkh(c.z, c.w));
    }
    for (int t = tid; t < 512; t += 256) {
        int r = t >> 4, j2 = t & 15;
        if (base + r < N_NODES) {
            float4 xv = ((const float4*)x)[(size_t)(base + r) * 16 + j2];
            xs2[r][j2] = make_uint2(pkh(xv.x, xv.y), pkh(xv.z, xv.w));
        }
    }
    __syncthreads();

    const int wv = tid >> 6;
    const int d  = tid & 63;
    const float bqv = bq[d], bkv = bk[d], bvv = bv[d];

    half2v aq[8], ak[8], av[8];
    #pragma unroll
    for (int r = 0; r < 8; ++r) {
        aq[r] = (half2v)0; ak[r] = (half2v)0; av[r] = (half2v)0;
    }

    #pragma unroll 4
    for (int j2 = 0; j2 < 16; ++j2) {
        uint2 wq = WT[0][j2 * 64 + d];
        uint2 wk = WT[1][j2 * 64 + d];
        uint2 wvv = WT[2][j2 * 64 + d];
        half2v wq0 = u2h(wq.x), wq1 = u2h(wq.y);
        half2v wk0 = u2h(wk.x), wk1 = u2h(wk.y);
        half2v wv0 = u2h(wvv.x), wv1 = u2h(wvv.y);
        #pragma unroll
        for (int r = 0; r < 8; ++r) {
            uint2 xv = xs2[wv * 8 + r][j2];   // wave-uniform b64 broadcast
            half2v x0 = u2h(xv.x), x1 = u2h(xv.y);
            aq[r] = x0 * wq0 + (x1 * wq1 + aq[r]);   // 2x v_pk_fma_f16
            ak[r] = x0 * wk0 + (x1 * wk1 + ak[r]);
            av[r] = x0 * wv0 + (x1 * wv1 + av[r]);
        }
    }
    // Q (f16, pre-scaled by log2e) and K (f16) stores: coalesced 128B/wave
    float avf[8];
    #pragma unroll
    for (int r = 0; r < 8; ++r) {
        int n = base + wv * 8 + r;
        float q = (float)aq[r].x + (float)aq[r].y + bqv;
        float k = (float)ak[r].x + (float)ak[r].y + bkv;
        avf[r]  = (float)av[r].x + (float)av[r].y + bvv;
        if (n < N_NODES) {
            Qh[(size_t)n * 64 + d]  = f2h(q * 1.44269504f);
            KVC[(size_t)n * 128 + d] = f2h(k);
        }
    }
    // V: stage f16 in xs2 (reuse), repack {V,C} fp8 -> uint2 stores
    __syncthreads();   // all xs2 reads done
    unsigned int* vstage = (unsigned int*)xs2;
    #pragma unroll
    for (int r = 0; r < 8; ++r)
        ((unsigned short*)vstage)[(wv * 8 + r) * 64 + d] = f2h(avf[r]);
    __syncthreads();
    uint2* VC2 = (uint2*)KVC;           // row = 32 uint2 (256B)
    for (int t = tid; t < 512; t += 256) {
        int ln = t >> 4, j = t & 15;
        int n = base + ln;
        if (n < N_NODES) {
            uint2 vp = ((const uint2*)vstage)[ln * 16 + j];
            half2v v0 = u2h(vp.x), v1 = u2h(vp.y);
            float4 cv = ((const float4*)coord)[(size_t)n * 16 + j];
            uint2 o;
            o.x = pack4_fp8((float)v0.x, (float)v0.y,
                            (float)v1.x, (float)v1.y);
            o.y = pack4_fp8(cv.x, cv.y, cv.z, cv.w);
            VC2[(size_t)n * 32 + 16 + j] = o;
        }
    }
}

// Row-group-partitioned histogram (group ~ XCD; atomics L2-local)
__global__ __launch_bounds__(256) void k_hist(
    const int* __restrict__ eidx, int* __restrict__ counts)
{
    const int grp = blockIdx.x & (NGROUPS - 1);
    const int blk = blockIdx.x >> 3;
    const int nblk = gridDim.x >> 3;
    const int rlo = grp * ROWS_PER_GROUP;
    const int rhi = rlo + ROWS_PER_GROUP;
    for (int e = blk * 256 + threadIdx.x; e < NE; e += nblk * 256) {
        int r = eidx[e];
        if (r >= rlo && r < rhi) atomicAdd(counts + r, 1);
    }
}

__global__ __launch_bounds__(256) void k_scan1(
    const int* __restrict__ counts, int* __restrict__ offsets,
    int* __restrict__ bsums)
{
    __shared__ int tmp[256];
    int i = blockIdx.x * 256 + threadIdx.x;
    int v = (i < N_NODES) ? counts[i] : 0;
    tmp[threadIdx.x] = v;
    __syncthreads();
    #pragma unroll
    for (int off = 1; off < 256; off <<= 1) {
        int t = (threadIdx.x >= off) ? tmp[threadIdx.x - off] : 0;
        __syncthreads();
        tmp[threadIdx.x] += t;
        __syncthreads();
    }
    if (i < N_NODES) offsets[i] = tmp[threadIdx.x] - v;   // exclusive
    if (threadIdx.x == 255) bsums[blockIdx.x] = tmp[255];
}

// merged scan2+scan3
__global__ __launch_bounds__(256) void k_scan23(
    int* __restrict__ offsets, int* __restrict__ counts,
    const int* __restrict__ bsums)
{
    __shared__ int red[4];
    const int tid = threadIdx.x;
    const int b   = blockIdx.x;
    int v = (tid < b && tid < NSCAN_BLOCKS) ? bsums[tid] : 0;
    #pragma unroll
    for (int off = 32; off; off >>= 1) v += __shfl_xor(v, off);
    if ((tid & 63) == 0) red[tid >> 6] = v;
    __syncthreads();
    const int pre = red[0] + red[1] + red[2] + red[3];

    int i = b * 256 + tid;
    if (i < N_NODES) {
        int o = offsets[i] + pre;
        offsets[i] = o;
        counts[i]  = o;     // cursor for fill
    }
    if (i == 0) offsets[N_NODES] = NE;
}

// Row-group-partitioned fill (writes L2-local -> no 16x amplification)
__global__ __launch_bounds__(256) void k_fill(
    const int* __restrict__ eidx, int* __restrict__ cursor,
    int* __restrict__ bucket_col)
{
    const int grp = blockIdx.x & (NGROUPS - 1);
    const int blk = blockIdx.x >> 3;
    const int nblk = gridDim.x >> 3;
    const int rlo = grp * ROWS_PER_GROUP;
    const int rhi = rlo + ROWS_PER_GROUP;
    const int* __restrict__ cols = eidx + NE;
    for (int e = blk * 256 + threadIdx.x; e < NE; e += nblk * 256) {
        int r = eidx[e];
        if (r >= rlo && r < rhi) {
            int pos = atomicAdd(cursor + r, 1);
            bucket_col[pos] = cols[e];
        }
    }
}

// Fused edge pass: wave per node, 16-lane quarter per edge, lane = 4 dims,
// 2x unrolled (8-stride: MLP-vs-Poisson-tail sweet spot [R17]).
// K f16 (fdot2), V/C fp8 (one uint2 load), 2 lines/neighbor.
__global__ __launch_bounds__(256) void k_edge_fused(
    const int* __restrict__ bucket_col, const int* __restrict__ offsets,
    const unsigned short* __restrict__ Qh, const unsigned short* __restrict__ KVC,
    const float* __restrict__ coord,
    const float* __restrict__ Wc, const float* __restrict__ bc,
    float* __restrict__ out_x, float* __restrict__ out_c,
    float* __restrict__ wsum)
{
    const int lane = threadIdx.x & 63;
    const int n = (blockIdx.x * 256 + threadIdx.x) >> 6;
    if (n >= N_NODES) return;
    const int qt = lane >> 4;          // quarter: which edge of the group of 4
    const int sl = lane & 15;          // dim-quad slot (dims 4sl..4sl+3)

    const uint2 q2   = ((const uint2*)Qh)[(size_t)n * 16 + sl];   // 2x f16x2
    const float4 cr4 = ((const float4*)coord)[(size_t)n * 16 + sl];
    const float4 wc4 = ((const float4*)Wc)[sl];
    const float4 bc4 = ((const float4*)bc)[sl];
    const uint2* K2  = (const uint2*)KVC;    // K: idx c*32 + sl
    const uint2* VC2 = (const uint2*)KVC;    // VC: idx c*32 + 16 + sl

    const int s = offsets[n], t = offsets[n + 1];
    float4 accx = {0.f, 0.f, 0.f, 0.f};
    float4 accc = {0.f, 0.f, 0.f, 0.f};
    float psum = 0.0f;

    for (int base = s; base < t; base += 8) {
        int pos0 = base + qt;
        int pos1 = base + 4 + qt;
        bool v0 = pos0 < t, v1 = pos1 < t;
        int c0 = bucket_col[v0 ? pos0 : (t - 1)];
        int c1 = bucket_col[v1 ? pos1 : (t - 1)];
        uint2 k0  = K2[(size_t)c0 * 32 + sl];
        uint2 vc0 = VC2[(size_t)c0 * 32 + 16 + sl];
        uint2 k1  = K2[(size_t)c1 * 32 + sl];
        uint2 vc1 = VC2[(size_t)c1 * 32 + 16 + sl];

        v2f c0a = fp8x2<false>(vc0.y), c0b = fp8x2<true>(vc0.y);
        v2f c1a = fp8x2<false>(vc1.y), c1b = fp8x2<true>(vc1.y);

        // logits via f16 dot2 (Q pre-scaled by log2e -> exp2 later)
        float d0 = dot2acc(q2.y, k0.y, dot2acc(q2.x, k0.x, 0.0f));
        float d1 = dot2acc(q2.y, k1.y, dot2acc(q2.x, k1.x, 0.0f));

        float dx0x = cr4.x - c0a.x, dx0y = cr4.y - c0a.y;
        float dx0z = cr4.z - c0b.x, dx0w = cr4.w - c0b.y;
        float e0 = dx0x * dx0x + dx0y * dx0y + dx0z * dx0z + dx0w * dx0w;
        float dx1x = cr4.x - c1a.x, dx1y = cr4.y - c1a.y;
        float dx1z = cr4.z - c1b.x, dx1w = cr4.w - c1b.y;
        float e1 = dx1x * dx1x + dx1y * dx1y + dx1z * dx1z + dx1w * dx1w;

        #pragma unroll
        for (int off = 1; off <= 8; off <<= 1) {   // reduce within quarter
            d0 += __shfl_xor(d0, off);
            e0 += __shfl_xor(e0, off);
            d1 += __shfl_xor(d1, off);
            e1 += __shfl_xor(e1, off);
        }
        float p0e = v0 ? exp2f(d0) : 0.0f;
        float p1e = v1 ? exp2f(d1) : 0.0f;
        float dist0 = sqrtf(e0), dist1 = sqrtf(e1);
        psum += p0e + p1e;

        v2f v0a = fp8x2<false>(vc0.x), v0b = fp8x2<true>(vc0.x);
        v2f v1a = fp8x2<false>(vc1.x), v1b = fp8x2<true>(vc1.x);
        accx.x += p0e * v0a.x + p1e * v1a.x;
        accx.y += p0e * v0a.y + p1e * v1a.y;
        accx.z += p0e * v0b.x + p1e * v1b.x;
        accx.w += p0e * v0b.y + p1e * v1b.y;
        accc.x += p0e * (dist0 * wc4.x + bc4.x) * dx0x
                + p1e * (dist1 * wc4.x + bc4.x) * dx1x;
        accc.y += p0e * (dist0 * wc4.y + bc4.y) * dx0y
                + p1e * (dist1 * wc4.y + bc4.y) * dx1y;
        accc.z += p0e * (dist0 * wc4.z + bc4.z) * dx0z
                + p1e * (dist1 * wc4.z + bc4.z) * dx1z;
        accc.w += p0e * (dist0 * wc4.w + bc4.w) * dx0w
                + p1e * (dist1 * wc4.w + bc4.w) * dx1w;
    }

    // cross-quarter combine (once per node)
    #pragma unroll
    for (int off = 16; off <= 32; off <<= 1) {
        accx.x += __shfl_xor(accx.x, off);
        accx.y += __shfl_xor(accx.y, off);
        accx.z += __shfl_xor(accx.z, off);
        accx.w += __shfl_xor(accx.w, off);
        accc.x += __shfl_xor(accc.x, off);
        accc.y += __shfl_xor(accc.y, off);
        accc.z += __shfl_xor(accc.z, off);
        accc.w += __shfl_xor(accc.w, off);
        psum   += __shfl_xor(psum, off);
    }
    if (lane < 16) {
        ((float4*)out_x)[(size_t)n * 16 + sl] = accx;   // unnormalized
        ((float4*)out_c)[(size_t)n * 16 + sl] = accc;
    }
    if (lane == 0) wsum[n] = psum;
}

// deterministic fixed-tree reduction of wsum -> S (single block)
__global__ __launch_bounds__(1024) void k_redsum(
    const float* __restrict__ wsum, float* __restrict__ S)
{
    __shared__ float red[16];
    float a = 0.0f;
    for (int i = threadIdx.x; i < N_NODES; i += 1024) a += wsum[i];
    #pragma unroll
    for (int off = 32; off; off >>= 1) a += __shfl_xor(a, off);
    if ((threadIdx.x & 63) == 0) red[threadIdx.x >> 6] = a;
    __syncthreads();
    if (threadIdx.x == 0) {
        float s = 0.0f;
        #pragma unroll
        for (int w = 0; w < 16; ++w) s += red[w];
        *S = s;
    }
}

// out = residual + out * (1/S), one float4 per thread
__global__ __launch_bounds__(256) void k_finalize(
    const float* __restrict__ x, const float* __restrict__ coord,
    const float* __restrict__ S, float* __restrict__ out)
{
    const float inv = 1.0f / *S;
    const int nd4 = (N_NODES * DIM) / 4;      // 800000
    const float4* x4 = (const float4*)x;
    const float4* c4 = (const float4*)coord;
    float4* o4 = (float4*)out;
    int i = blockIdx.x * 256 + threadIdx.x;
    if (i < 2 * nd4) {
        float4 r = (i < nd4) ? x4[i] : c4[i - nd4];
        float4 a = o4[i];
        a.x = r.x + a.x * inv;
        a.y = r.y + a.y * inv;
        a.z = r.z + a.z * inv;
        a.w = r.w + a.w * inv;
        o4[i] = a;
    }
}

extern "C" void kernel_launch(void* const* d_in, const int* in_sizes, int n_in,
                              void* d_out, int out_size, void* d_ws, size_t ws_size,
                              hipStream_t stream)
{
    const float* x     = (const float*)d_in[0];
    const float* coord = (const float*)d_in[1];
    const float* Wq    = (const float*)d_in[2];
    const float* bq    = (const float*)d_in[3];
    const float* Wk    = (const float*)d_in[4];
    const float* bk    = (const float*)d_in[5];
    const float* Wv    = (const float*)d_in[6];
    const float* bv    = (const float*)d_in[7];
    const float* Wc    = (const float*)d_in[8];
    const float* bc    = (const float*)d_in[9];
    const int*   eidx  = (const int*)d_in[10];

    float* out = (float*)d_out;
    float* ws  = (float*)d_ws;

    unsigned short* Qh  = (unsigned short*)ws;
    unsigned short* KVC = Qh + (size_t)N_NODES * 64;
    int* bucket_col = (int*)(KVC + (size_t)N_NODES * 128);   // 256B rows
    int* counts  = bucket_col + NE;
    int* offsets = counts + N_NODES;
    int* bsums   = offsets + N_NODES + 1;
    float* wsum  = (float*)(bsums + 256);
    float* S     = wsum + N_NODES;

    float* out_x = out;
    float* out_c = out + (size_t)N_NODES * DIM;

    // node projections + packing FIRST (also zeros counts -> no memset)
    k_qkv<<<(N_NODES + 31) / 32, 256, 0, stream>>>(
        x, coord, Wq, bq, Wk, bk, Wv, bv, Qh, KVC, counts);

    // CSR build (row-bucketed column list), row-group-partitioned scatter
    k_hist  <<<NFILL_GRID, 256, 0, stream>>>(eidx, counts);
    k_scan1 <<<NSCAN_BLOCKS, 256, 0, stream>>>(counts, offsets, bsums);
    k_scan23<<<NSCAN_BLOCKS, 256, 0, stream>>>(offsets, counts, bsums);
    k_fill  <<<NFILL_GRID, 256, 0, stream>>>(eidx, counts, bucket_col);

    // fused edge pass (quarter-per-edge, 2x unrolled), acc -> d_out
    k_edge_fused<<<(N_NODES * 64 + 255) / 256, 256, 0, stream>>>(
        bucket_col, offsets, Qh, KVC, coord, Wc, bc, out_x, out_c, wsum);

    // deterministic global sum, then normalize + residual
    k_redsum<<<1, 1024, 0, stream>>>(wsum, S);
    k_finalize<<<(2 * N_NODES * DIM / 4 + 255) / 256, 256, 0, stream>>>(
        x, coord, S, out);
}